// Round 22
// baseline (46.753 us; speedup 1.0000x reference)
//
#include <hip/hip_runtime.h>
#include <hip/hip_bf16.h>
#include <stdint.h>
#include <math.h>

#define N_HEADS 16
#define HEAD_DIM 64
#define SEQ_LEN 2048
#define NTILE_TOT 64                // 32-row image tiles per head
#define NTQ 16                      // tiles per quarter-stream (512 kv / 32)

typedef __bf16 bf16x8 __attribute__((ext_vector_type(8)));
typedef __bf16 bf16x4 __attribute__((ext_vector_type(4)));
typedef short  s16x4  __attribute__((ext_vector_type(4)));
typedef float  f32x4  __attribute__((ext_vector_type(4)));
typedef float  f32x16 __attribute__((ext_vector_type(16)));

#if __has_builtin(__builtin_amdgcn_mfma_f32_32x32x8bf16_1k)
#define HAVE_K8 1
#else
#define HAVE_K8 0
#endif

#if __has_builtin(__builtin_amdgcn_global_load_lds)
#define HAVE_GLL 1
#define GLL16(gsrc, ldst)                                                     \
    __builtin_amdgcn_global_load_lds(                                         \
        (const __attribute__((address_space(1))) void*)(gsrc),                \
        (__attribute__((address_space(3))) void*)(ldst), 16, 0, 0)
#else
#define HAVE_GLL 0
#endif

static __device__ __forceinline__ unsigned pkbf(float a, float b) {
    union { __bf16 h[2]; unsigned u; } t;
    t.h[0] = (__bf16)a; t.h[1] = (__bf16)b;
    return t.u;
}

// Prep: swizzled bf16 images, 4 KB block per (head, 32-row tile).
//   K : row-major bf16 [32][64], addr = row*128 + (off ^ ((row&7)<<4))
//   Vt: transposed bf16 [64 d][32 k] PLAIN rows (R4-verified):
//       addr = (vc*64 + vr*2) ^ ((vc&7)<<4)
// Per-tile max ||K row||^2 via plain store (no atomics/memset - R18/19 lessons).
__global__ __launch_bounds__(256)
void prep_kernel(const float* __restrict__ k,
                 const float* __restrict__ v,
                 char* __restrict__ kimg,
                 char* __restrict__ vtimg,
                 float* __restrict__ tilemax) {
    const int ts  = blockIdx.x;
    const int h   = blockIdx.y;
    const int tid = threadIdx.x;
    const int s0  = ts * 32;
    const size_t blk = ((size_t)h * NTILE_TOT + ts) * 4096;

    __shared__ float redmax[4];

    const int krow = tid >> 3;
    const int kcol = (tid & 7) * 8;
    const float* ks = k + ((size_t)h * SEQ_LEN + s0 + krow) * HEAD_DIM + kcol;
    f32x4 a = *(const f32x4*)ks;
    f32x4 b = *(const f32x4*)(ks + 4);
    bf16x8 kb;
    float pn = 0.0f;
    #pragma unroll
    for (int i = 0; i < 4; ++i) {
        kb[i] = (__bf16)a[i]; kb[4 + i] = (__bf16)b[i];
        pn += a[i] * a[i] + b[i] * b[i];
    }
    *(bf16x8*)(kimg + blk + krow * 128 + ((kcol * 2) ^ ((krow & 7) << 4))) = kb;

    pn += __shfl_xor(pn, 1);
    pn += __shfl_xor(pn, 2);
    pn += __shfl_xor(pn, 4);
    float wmax = pn;
    wmax = fmaxf(wmax, __shfl_xor(wmax, 8));
    wmax = fmaxf(wmax, __shfl_xor(wmax, 16));
    wmax = fmaxf(wmax, __shfl_xor(wmax, 32));
    if ((tid & 63) == 0) redmax[tid >> 6] = wmax;

    const int vc = tid & 63;
    const int vr = (tid >> 6) * 8;
    const float* vs = v + ((size_t)h * SEQ_LEN + s0 + vr) * HEAD_DIM + vc;
    bf16x8 vb;
    #pragma unroll
    for (int j = 0; j < 8; ++j) vb[j] = (__bf16)vs[(size_t)j * HEAD_DIM];
    *(bf16x8*)(vtimg + blk + ((vc * 64 + vr * 2) ^ ((vc & 7) << 4))) = vb;

    __syncthreads();
    if (tid == 0) {
        tilemax[h * NTILE_TOT + ts] = fmaxf(fmaxf(redmax[0], redmax[1]),
                                            fmaxf(redmax[2], redmax[3]));
    }
}

// R22: 32x32 restructure. 8-wave WG = 2 q-groups (32 q each) x 4 KV quarters
// (512 kv, KVBLK=32, 16 iters). Each wave: QK^T = 4x mfma_32x32x16
// (A=K rows, B=Q prescaled by scale2) -> S^T lane holds q=lane&31,
// klocal(r) = (r&3)+8*(r>>2)+4*(lane>>5). Zero-shuffle PV: K=8 MFMA B-frag
// k-slots (l>>5)*4+b == C/D rows of regs 4j..4j+3 -> pb[j]=pack(p[4j..4j+3]).
// GLOBAL fixed softmax bound (kend=2047 for all quarters): early quarters'
// p underflow to exact 0 -> head-uniform global prefix skip Sg; barriers stay
// uniform via WG-uniform tmin (inactive waves idle at barriers).
// LDS 64KB: K [qtr][dbuf][4096] @0; Vt same @32768. Merge overlays 50KB.
template <bool IMG>
__global__ __launch_bounds__(512, 4)
void attn_alibi_kernel(const float* __restrict__ q,
                       const float* __restrict__ k,
                       const float* __restrict__ v,
                       float* __restrict__ out,
                       const char* __restrict__ kimg,
                       const char* __restrict__ vtimg,
                       const float* __restrict__ tilemax) {
    const int tid  = threadIdx.x;
    const int wave = tid >> 6;
    const int lane = tid & 63;
    const int q5   = lane & 31;
    const int hi   = lane >> 5;
    const int qtr  = wave >> 1;          // KV quarter 0..3
    const int G    = wave & 1;           // q-group

    const int h     = blockIdx.y;
    const int qbase = blockIdx.x * 64;
    const int qpos  = qbase + G * 32 + q5;
    const int kstart = qtr * 512;

    const float* qh = q + (size_t)h * SEQ_LEN * HEAD_DIM;
    const float* kh = k + (size_t)h * SEQ_LEN * HEAD_DIM;
    const float* vh = v + (size_t)h * SEQ_LEN * HEAD_DIM;

    __shared__ alignas(16) char smem[65536];
    char* kq = smem + qtr * 8192;
    char* vq = smem + 32768 + qtr * 8192;

    const float LOG2E  = 1.4426950408889634f;
    const float scale2 = 0.125f * LOG2E;
    const float slope  = exp2f(-0.5f * (float)(h + 1));
    const float slope2 = slope * LOG2E;

    // ---- Q B-fragments PRESCALED by scale2; ||q||^2 in f32 ----
    bf16x8 qf[4];
    float qn2 = 0.0f;
    {
        const float* qr = qh + (size_t)qpos * HEAD_DIM;
        #pragma unroll
        for (int c = 0; c < 4; ++c)
            #pragma unroll
            for (int b = 0; b < 8; ++b) {
                float x = qr[c * 16 + hi * 8 + b];
                qn2 += x * x;
                qf[c][b] = (__bf16)(x * scale2);
            }
    }
    qn2 += __shfl_xor(qn2, 32);

    // ---- GLOBAL fixed softmax bound (kend = 2047 for all quarters) ----
    float knmax;
    if constexpr (IMG) {
        float tm = tilemax[h * NTILE_TOT + lane];
        tm = fmaxf(tm, __shfl_xor(tm, 1));
        tm = fmaxf(tm, __shfl_xor(tm, 2));
        tm = fmaxf(tm, __shfl_xor(tm, 4));
        tm = fmaxf(tm, __shfl_xor(tm, 8));
        tm = fmaxf(tm, __shfl_xor(tm, 16));
        tm = fmaxf(tm, __shfl_xor(tm, 32));
        knmax = sqrtf(tm);
    } else {
        knmax = 16.0f;
    }
    const float m = slope2 * (float)(SEQ_LEN - 1 - qpos)
                  + scale2 * sqrtf(qn2) * knmax * 1.05f;

    // ---- global prefix skip: tile gt dead iff 32*slope2*(63-gt) > 160 ----
    const float lim = 160.0f / (slope2 * 32.0f);
    const int Sg   = max(0, (int)ceilf(63.0f - lim));
    const int Sl   = min(NTQ, max(0, Sg - qtr * NTQ));   // per-quarter start
    const int tmin = max(0, Sg - 3 * NTQ);               // WG-uniform (<=15)

    // sv = sacc[r] + baseH + slope2*(32*t + 8*(r>>2) + (r&3))
    const float baseH = slope2 * ((float)(kstart - qpos) + 4.0f * (float)hi) - m;
    const float s2x8  = slope2 * 8.0f;

    float l = 0.0f;
    f32x16 accA = (f32x16)0.0f;   // d-tile 0 (d 0..31)
    f32x16 accB = (f32x16)0.0f;   // d-tile 1 (d 32..63)

    // ---- staging setup: quarter's 2 waves stage 4KB K + 4KB V per iter ----
    const char* kis = nullptr; const char* vis = nullptr;
    char* kdstu = nullptr; char* vdstu = nullptr;
    if constexpr (IMG) {
        const size_t blk0 = ((size_t)h * NTILE_TOT + qtr * NTQ) * 4096;
        kis = kimg + blk0 + G * 2048 + lane * 16;   // + t*4096 + sub*1024
        vis = vtimg + blk0 + G * 2048 + lane * 16;
        kdstu = kq + G * 2048;                      // wave-uniform; HW adds lane*16
        vdstu = vq + G * 2048;
    }

    // ---- prologue: stage tile Sl into buf (Sl&1) ----
    if constexpr (IMG) {
#if HAVE_GLL
        if (Sl < NTQ) {
            const int b0 = Sl & 1;
            #pragma unroll
            for (int sub = 0; sub < 2; ++sub) {
                GLL16(kis + (size_t)Sl * 4096 + sub * 1024, kdstu + b0 * 4096 + sub * 1024);
                GLL16(vis + (size_t)Sl * 4096 + sub * 1024, vdstu + b0 * 4096 + sub * 1024);
            }
        }
#else
        if (Sl < NTQ) {
            const int b0 = Sl & 1;
            #pragma unroll
            for (int sub = 0; sub < 2; ++sub) {
                f32x4 kr = *(const f32x4*)(kis + (size_t)Sl * 4096 + sub * 1024);
                f32x4 vr = *(const f32x4*)(vis + (size_t)Sl * 4096 + sub * 1024);
                *(f32x4*)(kdstu + b0 * 4096 + sub * 1024 + lane * 16) = kr;
                *(f32x4*)(vdstu + b0 * 4096 + sub * 1024 + lane * 16) = vr;
            }
        }
#endif
    }
    __syncthreads();

    for (int t = tmin; t < NTQ; ++t) {
        const bool act = (t >= Sl);
        const int buf  = t & 1;

        if constexpr (IMG) {
#if HAVE_GLL
            if (act && t + 1 < NTQ) {
                const int nb = (t + 1) & 1;
                #pragma unroll
                for (int sub = 0; sub < 2; ++sub) {
                    GLL16(kis + (size_t)(t + 1) * 4096 + sub * 1024,
                          kdstu + nb * 4096 + sub * 1024);
                    GLL16(vis + (size_t)(t + 1) * 4096 + sub * 1024,
                          vdstu + nb * 4096 + sub * 1024);
                }
            }
#else
            if (act && t + 1 < NTQ) {
                const int nb = (t + 1) & 1;
                #pragma unroll
                for (int sub = 0; sub < 2; ++sub) {
                    f32x4 kr = *(const f32x4*)(kis + (size_t)(t + 1) * 4096 + sub * 1024);
                    f32x4 vr = *(const f32x4*)(vis + (size_t)(t + 1) * 4096 + sub * 1024);
                    *(f32x4*)(kdstu + nb * 4096 + sub * 1024 + lane * 16) = kr;
                    *(f32x4*)(vdstu + nb * 4096 + sub * 1024 + lane * 16) = vr;
                }
            }
#endif
        } else {
            // fallback: stage current tile synchronously (2 barriers/iter)
            if (act) {
                const int qt = tid & 127;
                const int s0 = kstart + t * 32;
                const int krow = qt >> 2, c4 = qt & 3;
                const float* ks = kh + (size_t)(s0 + krow) * HEAD_DIM + c4 * 16;
                bf16x8 kb0, kb1;
                #pragma unroll
                for (int i = 0; i < 8; ++i) { kb0[i] = (__bf16)ks[i]; kb1[i] = (__bf16)ks[8 + i]; }
                const int swk = (krow & 7) << 4;
                char* kd = kq + buf * 4096 + krow * 128;
                *(bf16x8*)(kd + ((c4 * 32) ^ swk))      = kb0;
                *(bf16x8*)(kd + ((c4 * 32 + 16) ^ swk)) = kb1;

                const int vc = qt & 63, vg = qt >> 6;
                const float* vs = vh + (size_t)(s0 + vg * 16) * HEAD_DIM + vc;
                bf16x8 v0, v1;
                #pragma unroll
                for (int j = 0; j < 8; ++j) {
                    v0[j] = (__bf16)vs[(size_t)j * HEAD_DIM];
                    v1[j] = (__bf16)vs[(size_t)(8 + j) * HEAD_DIM];
                }
                const int swv = (vc & 7) << 4;
                char* vd = vq + buf * 4096;
                *(bf16x8*)(vd + ((vc * 64 + vg * 32) ^ swv))      = v0;
                *(bf16x8*)(vd + ((vc * 64 + vg * 32 + 16) ^ swv)) = v1;
            }
            __syncthreads();
        }

        if (act) {
            // ---- S^T = K Q^T : 4x mfma_32x32x16 over d-tiles ----
            const char* kbuf = kq + buf * 4096;
            f32x16 sacc = (f32x16)0.0f;
            __builtin_amdgcn_s_setprio(1);
            #pragma unroll
            for (int dt2 = 0; dt2 < 4; ++dt2) {
                bf16x8 kf = *(const bf16x8*)(kbuf + q5 * 128
                                             + ((dt2 * 32 + hi * 16) ^ ((q5 & 7) << 4)));
                sacc = __builtin_amdgcn_mfma_f32_32x32x16_bf16(kf, qf[dt2], sacc, 0, 0, 0);
            }
            __builtin_amdgcn_s_setprio(0);

            // ---- p = exp2(sacc + alibi - m); per-lane l ----
            const float bt0 = baseH + slope2 * (float)(32 * t);
            float p[16], y = 0.0f;
            #pragma unroll
            for (int u = 0; u < 4; ++u) {
                const float bt = bt0 + s2x8 * (float)u;
                #pragma unroll
                for (int j = 0; j < 4; ++j) {
                    float sv = sacc[u * 4 + j] + (bt + slope2 * (float)j);
                    p[u * 4 + j] = __builtin_amdgcn_exp2f(sv);
                    y += p[u * 4 + j];
                }
            }
            l += y;

            const char* vbuf = vq + buf * 4096;
#if HAVE_K8
            // ---- ZERO-SHUFFLE PV: 8x mfma_32x32x8bf16_1k ----
            s16x4 pb[4];
            #pragma unroll
            for (int j = 0; j < 4; ++j) {
                bf16x4 pf;
                #pragma unroll
                for (int b = 0; b < 4; ++b) pf[b] = (__bf16)p[j * 4 + b];
                pb[j] = __builtin_bit_cast(s16x4, pf);
            }
            __builtin_amdgcn_s_setprio(1);
            #pragma unroll
            for (int j = 0; j < 4; ++j) {
                {   // d-tile 0
                    const int d = q5;
                    bf16x4 vf = *(const bf16x4*)(vbuf
                        + ((d * 64 + 16 * j + 8 * hi) ^ ((d & 7) << 4)));
                    accA = __builtin_amdgcn_mfma_f32_32x32x8bf16_1k(
                        __builtin_bit_cast(s16x4, vf), pb[j], accA, 0, 0, 0);
                }
                {   // d-tile 1
                    const int d = 32 + q5;
                    bf16x4 vf = *(const bf16x4*)(vbuf
                        + ((d * 64 + 16 * j + 8 * hi) ^ ((d & 7) << 4)));
                    accB = __builtin_amdgcn_mfma_f32_32x32x8bf16_1k(
                        __builtin_bit_cast(s16x4, vf), pb[j], accB, 0, 0, 0);
                }
            }
            __builtin_amdgcn_s_setprio(0);
#else
            // ---- fallback PV: shfl_xor(32) exchange + 4x mfma_32x32x16 ----
            unsigned own[4], own2[4], sw[4], sw2[4];
            #pragma unroll
            for (int u = 0; u < 4; ++u) {
                own[u]  = pkbf(p[4 * u + 0], p[4 * u + 1]);
                own2[u] = pkbf(p[4 * u + 2], p[4 * u + 3]);
                sw[u]   = __shfl_xor(own[u], 32);
                sw2[u]  = __shfl_xor(own2[u], 32);
            }
            __builtin_amdgcn_s_setprio(1);
            #pragma unroll
            for (int ko8 = 0; ko8 < 4; ko8 += 2) {
                unsigned w0 = hi ? sw[ko8 + 1]  : own[ko8];
                unsigned w1 = hi ? sw2[ko8 + 1] : own2[ko8];
                unsigned w2 = hi ? own[ko8 + 1] : sw[ko8];
                unsigned w3 = hi ? own2[ko8 + 1]: sw2[ko8];
                unsigned uarr[4] = {w0, w1, w2, w3};
                bf16x8 pf8;
                #pragma unroll
                for (int i = 0; i < 4; ++i) {
                    pf8[2 * i]     = __builtin_bit_cast(bf16x4, (unsigned long long)0)[0]; // placeholder
                }
                // build bf16x8 from 4 u32 words
                union { unsigned u[4]; bf16x8 v; } cvt;
                cvt.u[0] = w0; cvt.u[1] = w1; cvt.u[2] = w2; cvt.u[3] = w3;
                pf8 = cvt.v;
                #pragma unroll
                for (int dt = 0; dt < 2; ++dt) {
                    const int d = dt * 32 + q5;
                    bf16x8 vf = *(const bf16x8*)(vbuf
                        + ((d * 64 + ko8 * 16 + 16 * hi) ^ ((d & 7) << 4)));
                    if (dt == 0)
                        accA = __builtin_amdgcn_mfma_f32_32x32x16_bf16(vf, pf8, accA, 0, 0, 0);
                    else
                        accB = __builtin_amdgcn_mfma_f32_32x32x16_bf16(vf, pf8, accB, 0, 0, 0);
                }
            }
            __builtin_amdgcn_s_setprio(0);
#endif
        }
        __syncthreads();
    }

    // ---- deferred l reduction (k split across hi within wave) ----
    l += __shfl_xor(l, 32);

    // ---- 4-way quarter merge (flash combine, O^T layout col=q) ----
    float* eacc = (float*)smem;             // [qtr-1][64 q][64 d]
    float* eml  = (float*)(smem + 49152);   // [(qtr-1)*64 + q]*2

    if (qtr != 0) {
        float* ea = eacc + (size_t)(qtr - 1) * 4096 + (G * 32 + q5) * 64;
        #pragma unroll
        for (int u = 0; u < 4; ++u) {
            f32x4 sa = {accA[4 * u], accA[4 * u + 1], accA[4 * u + 2], accA[4 * u + 3]};
            f32x4 sb = {accB[4 * u], accB[4 * u + 1], accB[4 * u + 2], accB[4 * u + 3]};
            *(f32x4*)(ea + 8 * u + 4 * hi)      = sa;
            *(f32x4*)(ea + 32 + 8 * u + 4 * hi) = sb;
        }
        if (hi == 0) {
            eml[((qtr - 1) * 64 + G * 32 + q5) * 2 + 0] = m;
            eml[((qtr - 1) * 64 + G * 32 + q5) * 2 + 1] = l;
        }
    }
    __syncthreads();
    if (qtr == 0) {
        float mm = m, mi[3], li[3];
        #pragma unroll
        for (int i = 0; i < 3; ++i) {
            mi[i] = eml[(i * 64 + G * 32 + q5) * 2 + 0];
            li[i] = eml[(i * 64 + G * 32 + q5) * 2 + 1];
            mm = fmaxf(mm, mi[i]);
        }
        float a0 = __builtin_amdgcn_exp2f(m - mm);
        float lt = l * a0;
        float ai[3];
        #pragma unroll
        for (int i = 0; i < 3; ++i) {
            ai[i] = __builtin_amdgcn_exp2f(mi[i] - mm);
            lt += li[i] * ai[i];
        }
        const float inv = 1.0f / lt;
        float* orow = out + ((size_t)h * SEQ_LEN + qbase + G * 32 + q5) * HEAD_DIM;
        #pragma unroll
        for (int u = 0; u < 4; ++u) {
            f32x4 oa = {accA[4 * u], accA[4 * u + 1], accA[4 * u + 2], accA[4 * u + 3]};
            f32x4 ob = {accB[4 * u], accB[4 * u + 1], accB[4 * u + 2], accB[4 * u + 3]};
            oa *= a0; ob *= a0;
            #pragma unroll
            for (int i = 0; i < 3; ++i) {
                const float* ea = eacc + (size_t)i * 4096 + (G * 32 + q5) * 64;
                oa += *(const f32x4*)(ea + 8 * u + 4 * hi) * ai[i];
                ob += *(const f32x4*)(ea + 32 + 8 * u + 4 * hi) * ai[i];
            }
            *(f32x4*)(orow + 8 * u + 4 * hi)      = oa * inv;
            *(f32x4*)(orow + 32 + 8 * u + 4 * hi) = ob * inv;
        }
    }
}

extern "C" void kernel_launch(void* const* d_in, const int* in_sizes, int n_in,
                              void* d_out, int out_size, void* d_ws, size_t ws_size,
                              hipStream_t stream) {
    const float* q = (const float*)d_in[0];
    const float* k = (const float*)d_in[1];
    const float* v = (const float*)d_in[2];
    float* out = (float*)d_out;

    const size_t imgBytes = (size_t)N_HEADS * NTILE_TOT * 4096;   // 4 MiB each
    const size_t need = 2 * imgBytes + N_HEADS * NTILE_TOT * sizeof(float);

    dim3 grid(SEQ_LEN / 64, N_HEADS, 1);
    if (ws_size >= need) {
        char* kimg     = (char*)d_ws;
        char* vtimg    = kimg + imgBytes;
        float* tilemax = (float*)(vtimg + imgBytes);
        prep_kernel<<<dim3(NTILE_TOT, N_HEADS, 1), dim3(256, 1, 1), 0, stream>>>(
            k, v, kimg, vtimg, tilemax);
        attn_alibi_kernel<true><<<grid, dim3(512, 1, 1), 0, stream>>>(
            q, k, v, out, kimg, vtimg, tilemax);
    } else {
        attn_alibi_kernel<false><<<grid, dim3(512, 1, 1), 0, stream>>>(
            q, k, v, out, nullptr, nullptr, nullptr);
    }
}